// Round 6
// baseline (262.578 us; speedup 1.0000x reference)
//
#include <hip/hip_runtime.h>

// ---------------------------------------------------------------------------
// CausalSelfAttention: B=2, T=2048, C=1024, H=16, HD=64
// Inputs fp32, output fp32; internal bf16 MFMA.
// R6: attn = R5 softmax + vectorized V staging + P-aliased-into-K LDS (35KB,
//     4 blk/CU). GEMM = m97 global_load_lds with wave-uniform dest (R4 bug:
//     lane-varying dest -> compiler waterfall; fixed per m104).
// ---------------------------------------------------------------------------

#define B_   2
#define T_   2048
#define C_   1024
#define H_   16
#define HD_  64
#define BT_  (B_ * T_)      // 4096
#define C3_  (3 * C_)       // 3072

typedef __attribute__((ext_vector_type(8))) __bf16 bf16x8;
typedef __attribute__((ext_vector_type(4))) float  f32x4;
typedef __attribute__((ext_vector_type(8))) unsigned short u16x8;

__device__ __forceinline__ unsigned short f2bf(float f) {
    unsigned int u = __float_as_uint(f);
    u = (u + 0x7fffu + ((u >> 16) & 1u)) >> 16;
    return (unsigned short)u;
}
__device__ __forceinline__ unsigned short bfc(float f) {
    return __builtin_bit_cast(unsigned short, (__bf16)f);
}

#define GLOAD16(g, l) __builtin_amdgcn_global_load_lds(                          \
    (const __attribute__((address_space(1))) unsigned int*)(g),                  \
    (__attribute__((address_space(3))) unsigned int*)(l), 16, 0, 0)

// ---------------- fused fp32 -> bf16 converts (one launch) -----------------
#define NX8  (BT_ * C_ / 8)      // 524288
#define NWA8 (C3_ * C_ / 8)      // 393216
#define NWP8 (C_ * C_ / 8)       // 131072
__global__ __launch_bounds__(256) void cvt3(const float* __restrict__ x,
                                            const float* __restrict__ wa,
                                            const float* __restrict__ wp,
                                            unsigned short* __restrict__ ox,
                                            unsigned short* __restrict__ owa,
                                            unsigned short* __restrict__ owp) {
    int i = blockIdx.x * 256 + threadIdx.x;
    const float* in;
    unsigned short* out;
    int j;
    if (i < NX8)             { in = x;  out = ox;  j = i; }
    else if (i < NX8 + NWA8) { in = wa; out = owa; j = i - NX8; }
    else                     { in = wp; out = owp; j = i - NX8 - NWA8; }
    const float4* p = (const float4*)in;
    float4 f0 = p[j * 2];
    float4 f1 = p[j * 2 + 1];
    u16x8 o;
    o[0] = f2bf(f0.x); o[1] = f2bf(f0.y); o[2] = f2bf(f0.z); o[3] = f2bf(f0.w);
    o[4] = f2bf(f1.x); o[5] = f2bf(f1.y); o[6] = f2bf(f1.z); o[7] = f2bf(f1.w);
    ((u16x8*)out)[j] = o;
}

// ---------------- bf16 GEMM: C[M][N] = A[M][K] * B[N][K]^T + bias ----------
// m97 structure: 128x128 tile, BK=64, global_load_lds dwordx4 into linear
// [128][64] LDS. Dest is WAVE-UNIFORM (m104); lane covers base + lane*16B.
template<int OUT_BF16>
__global__ __launch_bounds__(256) void gemm_lds(const unsigned short* __restrict__ A,
                                                const unsigned short* __restrict__ Bm,
                                                const float* __restrict__ bias,
                                                void* __restrict__ Cv,
                                                int M, int N, int K) {
    __shared__ __align__(16) unsigned short As[128][64];
    __shared__ __align__(16) unsigned short Bs[128][64];

    const int t    = threadIdx.x;
    const int lane = t & 63;
    const int w    = t >> 6;
    const int wr   = w & 1;
    const int wc   = w >> 1;
    const int l15  = lane & 15;
    const int lhi  = lane >> 4;
    const int m0   = blockIdx.y * 128;
    const int n0   = blockIdx.x * 128;
    const int lr8  = lane >> 3;          // 0..7  (row within 8-row stripe)
    const int lc8  = (lane & 7) * 8;     // 0,8,..,56 (u16 col)

    f32x4 acc[4][4] = {};

    for (int kb = 0; kb < K; kb += 64) {
        __syncthreads();
        #pragma unroll
        for (int i = 0; i < 4; ++i) {
            const int row = w * 32 + i * 8;                      // wave-uniform
            GLOAD16(A  + (size_t)(m0 + row + lr8) * K + kb + lc8, &As[row][0]);
            GLOAD16(Bm + (size_t)(n0 + row + lr8) * K + kb + lc8, &Bs[row][0]);
        }
        __syncthreads();   // compiler drains vmcnt before barrier
        #pragma unroll
        for (int kk = 0; kk < 2; ++kk) {
            bf16x8 af[4], bfm[4];
            #pragma unroll
            for (int m = 0; m < 4; ++m)
                af[m] = *(const bf16x8*)(&As[wr * 64 + m * 16 + l15][kk * 32 + lhi * 8]);
            #pragma unroll
            for (int n = 0; n < 4; ++n)
                bfm[n] = *(const bf16x8*)(&Bs[wc * 64 + n * 16 + l15][kk * 32 + lhi * 8]);
            #pragma unroll
            for (int m = 0; m < 4; ++m)
                #pragma unroll
                for (int n = 0; n < 4; ++n)
                    acc[m][n] = __builtin_amdgcn_mfma_f32_16x16x32_bf16(af[m], bfm[n], acc[m][n], 0, 0, 0);
        }
    }

    #pragma unroll
    for (int n = 0; n < 4; ++n) {
        int cg = n0 + wc * 64 + n * 16 + l15;
        float bv = bias[cg];
        #pragma unroll
        for (int m = 0; m < 4; ++m) {
            #pragma unroll
            for (int i = 0; i < 4; ++i) {
                int rg  = m0 + wr * 64 + m * 16 + lhi * 4 + i;
                float v = acc[m][n][i] + bv;
                if (OUT_BF16)
                    ((unsigned short*)Cv)[(size_t)rg * N + cg] = f2bf(v);
                else
                    ((float*)Cv)[(size_t)rg * N + cg] = v;
            }
        }
    }
}

// ---------------- causal flash attention -----------------------------------
// grid = (T/64, B*H); block 256 (4 waves x 16 q-rows). KV tiles of 128.
// Swapped QK^T (lane owns one q-row; in-lane softmax).
// LDS 35 KB: Ks[128][72] (P buffers alias it after barrier [C]) + Vt[64][136].
__global__ __launch_bounds__(256) void attn_fwd(const unsigned short* __restrict__ qkv,
                                                unsigned short* __restrict__ y) {
    __shared__ __align__(16) unsigned short Ks[128][72];   // 18432 B; P aliases
    __shared__ __align__(16) unsigned short Vt[64][136];   // 17408 B; [d][key]

    const int t    = threadIdx.x;
    const int lane = t & 63;
    const int wv   = t >> 6;
    const int l15  = lane & 15;
    const int lhi  = lane >> 4;
    const int b    = blockIdx.y >> 4;
    const int h    = blockIdx.y & 15;
    const int qt   = gridDim.x - 1 - blockIdx.x;  // biggest tiles first
    const int q0   = qt * 64;
    const size_t rowbase = (size_t)b * T_ * C3_;
    const int hoff = h * HD_;
    // wave-private P: 16 q-rows x 136 keys, aliased into Ks region
    unsigned short* PsW = &Ks[0][0] + wv * (16 * 136);

    bf16x8 qf[2];
    {
        int qrow = q0 + wv * 16 + l15;
        const unsigned short* qp = qkv + rowbase + (size_t)qrow * C3_ + hoff + lhi * 8;
        qf[0] = *(const bf16x8*)(qp);
        qf[1] = *(const bf16x8*)(qp + 32);
    }

    float Mx = -1e30f, Lx = 0.f;     // per-lane: q-row = q0 + wv*16 + l15
    f32x4 oacc[4];
    #pragma unroll
    for (int n = 0; n < 4; ++n) oacc[n] = f32x4{0.f, 0.f, 0.f, 0.f};

    const unsigned short* krow  = qkv + rowbase + C_ + hoff;
    const unsigned short* vbase = qkv + rowbase + 2 * C_ + hoff;
    const int vm = t >> 2;      // key-pair 0..63
    const int vc = t & 3;       // d-chunk (16 d each)

    const float SCL = 0.18033688f;   // 0.125 * log2(e)

    const int niter = (qt + 2) >> 1;
    for (int it = 0; it < niter; ++it) {
        const int k0 = it * 128;
        __syncthreads();                               // [A] prev PV (Ps/Vt reads) done
        // K tile: coalesced b128 row loads
        #pragma unroll
        for (int i = 0; i < 4; ++i) {
            int g   = i * 256 + t;
            int row = g >> 3;
            int kc  = g & 7;
            *(uint4*)(&Ks[row][kc * 8]) =
                *(const uint4*)(krow + (size_t)(k0 + row) * C3_ + kc * 8);
        }
        // V tile: vectorized row loads (2 rows x 16 d per thread) + packed
        // u32 transpose writes (2 keys per write)
        {
            const unsigned short* r0 = vbase + (size_t)(k0 + 2 * vm) * C3_ + vc * 16;
            const unsigned short* r1 = r0 + C3_;
            u16x8 a0 = *(const u16x8*)(r0);
            u16x8 a1 = *(const u16x8*)(r0 + 8);
            u16x8 b0 = *(const u16x8*)(r1);
            u16x8 b1 = *(const u16x8*)(r1 + 8);
            #pragma unroll
            for (int i = 0; i < 8; ++i) {
                *(unsigned int*)(&Vt[vc * 16 + i][2 * vm]) =
                    (unsigned int)a0[i] | ((unsigned int)b0[i] << 16);
                *(unsigned int*)(&Vt[vc * 16 + 8 + i][2 * vm]) =
                    (unsigned int)a1[i] | ((unsigned int)b1[i] << 16);
            }
        }
        __syncthreads();                               // [B] tile ready

        // S^T = K Q^T  (swapped: lane owns q-row l15)
        f32x4 sacc[8];
        #pragma unroll
        for (int n = 0; n < 8; ++n) sacc[n] = f32x4{0.f, 0.f, 0.f, 0.f};
        __builtin_amdgcn_s_setprio(1);
        #pragma unroll
        for (int kk = 0; kk < 2; ++kk) {
            #pragma unroll
            for (int n = 0; n < 8; ++n) {
                bf16x8 kf = *(const bf16x8*)(&Ks[n * 16 + l15][kk * 32 + lhi * 8]);
                sacc[n] = __builtin_amdgcn_mfma_f32_16x16x32_bf16(kf, qf[kk], sacc[n], 0, 0, 0);
            }
        }
        __builtin_amdgcn_s_setprio(0);
        __syncthreads();                               // [C] Ks reads done -> P may alias

        // scale (log2 domain) + causal mask
        const int qg = q0 + wv * 16 + l15;
        if (k0 + 127 <= q0) {
            #pragma unroll
            for (int n = 0; n < 8; ++n)
                #pragma unroll
                for (int r = 0; r < 4; ++r)
                    sacc[n][r] *= SCL;
        } else {
            #pragma unroll
            for (int n = 0; n < 8; ++n) {
                int kg = k0 + n * 16 + lhi * 4;
                #pragma unroll
                for (int r = 0; r < 4; ++r)
                    sacc[n][r] = (kg + r <= qg) ? sacc[n][r] * SCL : -1e30f;
            }
        }

        // in-lane softmax (32 vals) + 2-round cross-group reduce
        float vmx = sacc[0][0];
        #pragma unroll
        for (int n = 0; n < 8; ++n)
            #pragma unroll
            for (int r = 0; r < 4; ++r) vmx = fmaxf(vmx, sacc[n][r]);
        vmx = fmaxf(vmx, __shfl_xor(vmx, 16));
        vmx = fmaxf(vmx, __shfl_xor(vmx, 32));
        float Mn = fmaxf(Mx, vmx);
        float al = exp2f(Mx - Mn);
        Mx = Mn;
        float rs = 0.f;
        #pragma unroll
        for (int n = 0; n < 8; ++n)
            #pragma unroll
            for (int r = 0; r < 4; ++r) {
                float e = exp2f(sacc[n][r] - Mn);
                sacc[n][r] = e;
                rs += e;
            }
        rs += __shfl_xor(rs, 16);
        rs += __shfl_xor(rs, 32);
        Lx = Lx * al + rs;

        // rescale O (oacc rows are q = lhi*4 + r)
        #pragma unroll
        for (int r = 0; r < 4; ++r) {
            float ar = __shfl(al, lhi * 4 + r);
            #pragma unroll
            for (int nd = 0; nd < 4; ++nd) oacc[nd][r] *= ar;
        }

        // P -> aliased LDS: packed b64 writes (cvt via __bf16 casts)
        #pragma unroll
        for (int n = 0; n < 8; ++n) {
            unsigned int lo = (unsigned int)bfc(sacc[n][0]) | ((unsigned int)bfc(sacc[n][1]) << 16);
            unsigned int hi = (unsigned int)bfc(sacc[n][2]) | ((unsigned int)bfc(sacc[n][3]) << 16);
            uint2 pk; pk.x = lo; pk.y = hi;
            *(uint2*)(PsW + l15 * 136 + n * 16 + lhi * 4) = pk;
        }
        asm volatile("s_waitcnt lgkmcnt(0)" ::: "memory");

        __builtin_amdgcn_s_setprio(1);
        #pragma unroll
        for (int kk = 0; kk < 4; ++kk) {
            bf16x8 pf = *(const bf16x8*)(PsW + l15 * 136 + kk * 32 + lhi * 8);
            #pragma unroll
            for (int nd = 0; nd < 4; ++nd) {
                bf16x8 vf = *(const bf16x8*)(&Vt[nd * 16 + l15][kk * 32 + lhi * 8]);
                oacc[nd] = __builtin_amdgcn_mfma_f32_16x16x32_bf16(pf, vf, oacc[nd], 0, 0, 0);
            }
        }
        __builtin_amdgcn_s_setprio(0);
    }

    // epilogue: O / L -> y; L lives at lane q = lhi*4+i
    #pragma unroll
    for (int i = 0; i < 4; ++i) {
        float Lr = __shfl(Lx, lhi * 4 + i);
        float rL = 1.0f / Lr;
        #pragma unroll
        for (int nd = 0; nd < 4; ++nd) {
            int qg = q0 + wv * 16 + lhi * 4 + i;
            y[(size_t)(b * T_ + qg) * C_ + hoff + nd * 16 + l15] = bfc(oacc[nd][i] * rL);
        }
    }
}

// ---------------------------------------------------------------------------
extern "C" void kernel_launch(void* const* d_in, const int* in_sizes, int n_in,
                              void* d_out, int out_size, void* d_ws, size_t ws_size,
                              hipStream_t stream) {
    const float* x      = (const float*)d_in[0];
    const float* W_attn = (const float*)d_in[1];
    const float* b_attn = (const float*)d_in[2];
    const float* W_proj = (const float*)d_in[3];
    const float* b_proj = (const float*)d_in[4];
    float* out = (float*)d_out;

    char* ws = (char*)d_ws;
    unsigned short* xb   = (unsigned short*)(ws);                       // 4096x1024
    unsigned short* wab  = (unsigned short*)(ws + 8388608);             // 3072x1024
    unsigned short* wpb  = (unsigned short*)(ws + 8388608 + 6291456);   // 1024x1024
    unsigned short* qkvb = (unsigned short*)(ws + 16777216);            // 4096x3072
    unsigned short* yb   = (unsigned short*)(ws + 16777216 + 25165824); // 4096x1024

    cvt3<<<(NX8 + NWA8 + NWP8) / 256, 256, 0, stream>>>(x, W_attn, W_proj, xb, wab, wpb);

    gemm_lds<1><<<dim3(C3_ / 128, BT_ / 128), 256, 0, stream>>>(xb, wab, b_attn, qkvb, BT_, C3_, C_);

    attn_fwd<<<dim3(T_ / 64, B_ * H_), 256, 0, stream>>>(qkvb, yb);

    gemm_lds<0><<<dim3(C_ / 128, BT_ / 128), 256, 0, stream>>>(yb, wpb, b_proj, out, BT_, C_, C_);
}

// Round 7
// 220.946 us; speedup vs baseline: 1.1884x; 1.1884x over previous
//
#include <hip/hip_runtime.h>

// ---------------------------------------------------------------------------
// CausalSelfAttention: B=2, T=2048, C=1024, H=16, HD=64
// Inputs fp32, output fp32; internal bf16 MFMA.
// R7 = R6 + causal work-balancing: each block handles the q-tile pair
//      (bx, NT-1-bx) sequentially -> every block does exactly 17 KV-iters.
//      (R6 counters: Occupancy 11% time-avg = triangular imbalance with all
//       1024 blocks co-resident; pairing makes 512 uniform blocks, 2/CU.)
// ---------------------------------------------------------------------------

#define B_   2
#define T_   2048
#define C_   1024
#define H_   16
#define HD_  64
#define BT_  (B_ * T_)      // 4096
#define C3_  (3 * C_)       // 3072
#define NT_  (T_ / 64)      // 32 q-tiles

typedef __attribute__((ext_vector_type(8))) __bf16 bf16x8;
typedef __attribute__((ext_vector_type(4))) float  f32x4;
typedef __attribute__((ext_vector_type(8))) unsigned short u16x8;

__device__ __forceinline__ unsigned short f2bf(float f) {
    unsigned int u = __float_as_uint(f);
    u = (u + 0x7fffu + ((u >> 16) & 1u)) >> 16;
    return (unsigned short)u;
}
__device__ __forceinline__ unsigned short bfc(float f) {
    return __builtin_bit_cast(unsigned short, (__bf16)f);
}

#define GLOAD16(g, l) __builtin_amdgcn_global_load_lds(                          \
    (const __attribute__((address_space(1))) unsigned int*)(g),                  \
    (__attribute__((address_space(3))) unsigned int*)(l), 16, 0, 0)

// ---------------- fused fp32 -> bf16 converts (one launch) -----------------
#define NX8  (BT_ * C_ / 8)      // 524288
#define NWA8 (C3_ * C_ / 8)      // 393216
#define NWP8 (C_ * C_ / 8)       // 131072
__global__ __launch_bounds__(256) void cvt3(const float* __restrict__ x,
                                            const float* __restrict__ wa,
                                            const float* __restrict__ wp,
                                            unsigned short* __restrict__ ox,
                                            unsigned short* __restrict__ owa,
                                            unsigned short* __restrict__ owp) {
    int i = blockIdx.x * 256 + threadIdx.x;
    const float* in;
    unsigned short* out;
    int j;
    if (i < NX8)             { in = x;  out = ox;  j = i; }
    else if (i < NX8 + NWA8) { in = wa; out = owa; j = i - NX8; }
    else                     { in = wp; out = owp; j = i - NX8 - NWA8; }
    const float4* p = (const float4*)in;
    float4 f0 = p[j * 2];
    float4 f1 = p[j * 2 + 1];
    u16x8 o;
    o[0] = f2bf(f0.x); o[1] = f2bf(f0.y); o[2] = f2bf(f0.z); o[3] = f2bf(f0.w);
    o[4] = f2bf(f1.x); o[5] = f2bf(f1.y); o[6] = f2bf(f1.z); o[7] = f2bf(f1.w);
    ((u16x8*)out)[j] = o;
}

// ---------------- bf16 GEMM: C[M][N] = A[M][K] * B[N][K]^T + bias ----------
// m97 structure: 128x128 tile, BK=64, global_load_lds dwordx4 into linear
// [128][64] LDS. Dest is WAVE-UNIFORM (m104); lane covers base + lane*16B.
template<int OUT_BF16>
__global__ __launch_bounds__(256) void gemm_lds(const unsigned short* __restrict__ A,
                                                const unsigned short* __restrict__ Bm,
                                                const float* __restrict__ bias,
                                                void* __restrict__ Cv,
                                                int M, int N, int K) {
    __shared__ __align__(16) unsigned short As[128][64];
    __shared__ __align__(16) unsigned short Bs[128][64];

    const int t    = threadIdx.x;
    const int lane = t & 63;
    const int w    = t >> 6;
    const int wr   = w & 1;
    const int wc   = w >> 1;
    const int l15  = lane & 15;
    const int lhi  = lane >> 4;
    const int m0   = blockIdx.y * 128;
    const int n0   = blockIdx.x * 128;
    const int lr8  = lane >> 3;          // 0..7
    const int lc8  = (lane & 7) * 8;     // 0,8,..,56

    f32x4 acc[4][4] = {};

    for (int kb = 0; kb < K; kb += 64) {
        __syncthreads();
        #pragma unroll
        for (int i = 0; i < 4; ++i) {
            const int row = w * 32 + i * 8;                      // wave-uniform
            GLOAD16(A  + (size_t)(m0 + row + lr8) * K + kb + lc8, &As[row][0]);
            GLOAD16(Bm + (size_t)(n0 + row + lr8) * K + kb + lc8, &Bs[row][0]);
        }
        __syncthreads();
        #pragma unroll
        for (int kk = 0; kk < 2; ++kk) {
            bf16x8 af[4], bfm[4];
            #pragma unroll
            for (int m = 0; m < 4; ++m)
                af[m] = *(const bf16x8*)(&As[wr * 64 + m * 16 + l15][kk * 32 + lhi * 8]);
            #pragma unroll
            for (int n = 0; n < 4; ++n)
                bfm[n] = *(const bf16x8*)(&Bs[wc * 64 + n * 16 + l15][kk * 32 + lhi * 8]);
            #pragma unroll
            for (int m = 0; m < 4; ++m)
                #pragma unroll
                for (int n = 0; n < 4; ++n)
                    acc[m][n] = __builtin_amdgcn_mfma_f32_16x16x32_bf16(af[m], bfm[n], acc[m][n], 0, 0, 0);
        }
    }

    #pragma unroll
    for (int n = 0; n < 4; ++n) {
        int cg = n0 + wc * 64 + n * 16 + l15;
        float bv = bias[cg];
        #pragma unroll
        for (int m = 0; m < 4; ++m) {
            #pragma unroll
            for (int i = 0; i < 4; ++i) {
                int rg  = m0 + wr * 64 + m * 16 + lhi * 4 + i;
                float v = acc[m][n][i] + bv;
                if (OUT_BF16)
                    ((unsigned short*)Cv)[(size_t)rg * N + cg] = f2bf(v);
                else
                    ((float*)Cv)[(size_t)rg * N + cg] = v;
            }
        }
    }
}

// ---------------- causal flash attention -----------------------------------
// grid = (NT/2, B*H); block 256 (4 waves x 16 q-rows). KV tiles of 128.
// Each block: q-tile bx, then q-tile NT-1-bx (17 KV-iters total, uniform).
// Swapped QK^T (lane owns one q-row; in-lane softmax).
// LDS 35 KB: Ks[128][72] (P aliases after barrier [C]) + Vt[64][136].
__global__ __launch_bounds__(256) void attn_fwd(const unsigned short* __restrict__ qkv,
                                                unsigned short* __restrict__ y) {
    __shared__ __align__(16) unsigned short Ks[128][72];   // 18432 B; P aliases
    __shared__ __align__(16) unsigned short Vt[64][136];   // 17408 B; [d][key]

    const int t    = threadIdx.x;
    const int lane = t & 63;
    const int wv   = t >> 6;
    const int l15  = lane & 15;
    const int lhi  = lane >> 4;
    const int b    = blockIdx.y >> 4;
    const int h    = blockIdx.y & 15;
    const size_t rowbase = (size_t)b * T_ * C3_;
    const int hoff = h * HD_;
    unsigned short* PsW = &Ks[0][0] + wv * (16 * 136);  // wave-private P 16x136

    const unsigned short* krow  = qkv + rowbase + C_ + hoff;
    const unsigned short* vbase = qkv + rowbase + 2 * C_ + hoff;
    const int vm = t >> 2;      // key-pair 0..63
    const int vc = t & 3;       // d-chunk (16 d each)
    const float SCL = 0.18033688f;   // 0.125 * log2(e)

    #pragma unroll 1
    for (int half = 0; half < 2; ++half) {
        const int qt = half ? (NT_ - 1 - (int)blockIdx.x) : (int)blockIdx.x;
        const int q0 = qt * 64;

        bf16x8 qf[2];
        {
            int qrow = q0 + wv * 16 + l15;
            const unsigned short* qp = qkv + rowbase + (size_t)qrow * C3_ + hoff + lhi * 8;
            qf[0] = *(const bf16x8*)(qp);
            qf[1] = *(const bf16x8*)(qp + 32);
        }

        float Mx = -1e30f, Lx = 0.f;     // per-lane: q-row = q0 + wv*16 + l15
        f32x4 oacc[4];
        #pragma unroll
        for (int n = 0; n < 4; ++n) oacc[n] = f32x4{0.f, 0.f, 0.f, 0.f};

        const int niter = (qt + 2) >> 1;
        for (int it = 0; it < niter; ++it) {
            const int k0 = it * 128;
            __syncthreads();                           // [A] prev PV reads done
            // K tile: coalesced b128 row loads
            #pragma unroll
            for (int i = 0; i < 4; ++i) {
                int g   = i * 256 + t;
                int row = g >> 3;
                int kc  = g & 7;
                *(uint4*)(&Ks[row][kc * 8]) =
                    *(const uint4*)(krow + (size_t)(k0 + row) * C3_ + kc * 8);
            }
            // V tile: vectorized row loads + packed u32 transpose writes
            {
                const unsigned short* r0 = vbase + (size_t)(k0 + 2 * vm) * C3_ + vc * 16;
                const unsigned short* r1 = r0 + C3_;
                u16x8 a0 = *(const u16x8*)(r0);
                u16x8 a1 = *(const u16x8*)(r0 + 8);
                u16x8 b0 = *(const u16x8*)(r1);
                u16x8 b1 = *(const u16x8*)(r1 + 8);
                #pragma unroll
                for (int i = 0; i < 8; ++i) {
                    *(unsigned int*)(&Vt[vc * 16 + i][2 * vm]) =
                        (unsigned int)a0[i] | ((unsigned int)b0[i] << 16);
                    *(unsigned int*)(&Vt[vc * 16 + 8 + i][2 * vm]) =
                        (unsigned int)a1[i] | ((unsigned int)b1[i] << 16);
                }
            }
            __syncthreads();                           // [B] tile ready

            // S^T = K Q^T  (swapped: lane owns q-row l15)
            f32x4 sacc[8];
            #pragma unroll
            for (int n = 0; n < 8; ++n) sacc[n] = f32x4{0.f, 0.f, 0.f, 0.f};
            __builtin_amdgcn_s_setprio(1);
            #pragma unroll
            for (int kk = 0; kk < 2; ++kk) {
                #pragma unroll
                for (int n = 0; n < 8; ++n) {
                    bf16x8 kf = *(const bf16x8*)(&Ks[n * 16 + l15][kk * 32 + lhi * 8]);
                    sacc[n] = __builtin_amdgcn_mfma_f32_16x16x32_bf16(kf, qf[kk], sacc[n], 0, 0, 0);
                }
            }
            __builtin_amdgcn_s_setprio(0);
            __syncthreads();                           // [C] Ks reads done -> P may alias

            // scale (log2 domain) + causal mask
            const int qg = q0 + wv * 16 + l15;
            if (k0 + 127 <= q0) {
                #pragma unroll
                for (int n = 0; n < 8; ++n)
                    #pragma unroll
                    for (int r = 0; r < 4; ++r)
                        sacc[n][r] *= SCL;
            } else {
                #pragma unroll
                for (int n = 0; n < 8; ++n) {
                    int kg = k0 + n * 16 + lhi * 4;
                    #pragma unroll
                    for (int r = 0; r < 4; ++r)
                        sacc[n][r] = (kg + r <= qg) ? sacc[n][r] * SCL : -1e30f;
                }
            }

            // in-lane softmax (32 vals) + 2-round cross-group reduce
            float vmx = sacc[0][0];
            #pragma unroll
            for (int n = 0; n < 8; ++n)
                #pragma unroll
                for (int r = 0; r < 4; ++r) vmx = fmaxf(vmx, sacc[n][r]);
            vmx = fmaxf(vmx, __shfl_xor(vmx, 16));
            vmx = fmaxf(vmx, __shfl_xor(vmx, 32));
            float Mn = fmaxf(Mx, vmx);
            float al = exp2f(Mx - Mn);
            Mx = Mn;
            float rs = 0.f;
            #pragma unroll
            for (int n = 0; n < 8; ++n)
                #pragma unroll
                for (int r = 0; r < 4; ++r) {
                    float e = exp2f(sacc[n][r] - Mn);
                    sacc[n][r] = e;
                    rs += e;
                }
            rs += __shfl_xor(rs, 16);
            rs += __shfl_xor(rs, 32);
            Lx = Lx * al + rs;

            // rescale O (oacc rows are q = lhi*4 + r)
            #pragma unroll
            for (int r = 0; r < 4; ++r) {
                float ar = __shfl(al, lhi * 4 + r);
                #pragma unroll
                for (int nd = 0; nd < 4; ++nd) oacc[nd][r] *= ar;
            }

            // P -> aliased LDS: packed b64 writes
            #pragma unroll
            for (int n = 0; n < 8; ++n) {
                unsigned int lo = (unsigned int)bfc(sacc[n][0]) | ((unsigned int)bfc(sacc[n][1]) << 16);
                unsigned int hi = (unsigned int)bfc(sacc[n][2]) | ((unsigned int)bfc(sacc[n][3]) << 16);
                uint2 pk; pk.x = lo; pk.y = hi;
                *(uint2*)(PsW + l15 * 136 + n * 16 + lhi * 4) = pk;
            }
            asm volatile("s_waitcnt lgkmcnt(0)" ::: "memory");

            __builtin_amdgcn_s_setprio(1);
            #pragma unroll
            for (int kk = 0; kk < 4; ++kk) {
                bf16x8 pf = *(const bf16x8*)(PsW + l15 * 136 + kk * 32 + lhi * 8);
                #pragma unroll
                for (int nd = 0; nd < 4; ++nd) {
                    bf16x8 vf = *(const bf16x8*)(&Vt[nd * 16 + l15][kk * 32 + lhi * 8]);
                    oacc[nd] = __builtin_amdgcn_mfma_f32_16x16x32_bf16(pf, vf, oacc[nd], 0, 0, 0);
                }
            }
            __builtin_amdgcn_s_setprio(0);
        }

        // epilogue: O / L -> y; L lives at lane q = lhi*4+i
        #pragma unroll
        for (int i = 0; i < 4; ++i) {
            float Lr = __shfl(Lx, lhi * 4 + i);
            float rL = 1.0f / Lr;
            #pragma unroll
            for (int nd = 0; nd < 4; ++nd) {
                int qg = q0 + wv * 16 + lhi * 4 + i;
                y[(size_t)(b * T_ + qg) * C_ + hoff + nd * 16 + l15] = bfc(oacc[nd][i] * rL);
            }
        }
    }
}

// ---------------------------------------------------------------------------
extern "C" void kernel_launch(void* const* d_in, const int* in_sizes, int n_in,
                              void* d_out, int out_size, void* d_ws, size_t ws_size,
                              hipStream_t stream) {
    const float* x      = (const float*)d_in[0];
    const float* W_attn = (const float*)d_in[1];
    const float* b_attn = (const float*)d_in[2];
    const float* W_proj = (const float*)d_in[3];
    const float* b_proj = (const float*)d_in[4];
    float* out = (float*)d_out;

    char* ws = (char*)d_ws;
    unsigned short* xb   = (unsigned short*)(ws);                       // 4096x1024
    unsigned short* wab  = (unsigned short*)(ws + 8388608);             // 3072x1024
    unsigned short* wpb  = (unsigned short*)(ws + 8388608 + 6291456);   // 1024x1024
    unsigned short* qkvb = (unsigned short*)(ws + 16777216);            // 4096x3072
    unsigned short* yb   = (unsigned short*)(ws + 16777216 + 25165824); // 4096x1024

    cvt3<<<(NX8 + NWA8 + NWP8) / 256, 256, 0, stream>>>(x, W_attn, W_proj, xb, wab, wpb);

    gemm_lds<1><<<dim3(C3_ / 128, BT_ / 128), 256, 0, stream>>>(xb, wab, b_attn, qkvb, BT_, C3_, C_);

    attn_fwd<<<dim3(NT_ / 2, B_ * H_), 256, 0, stream>>>(qkvb, yb);

    gemm_lds<0><<<dim3(C_ / 128, BT_ / 128), 256, 0, stream>>>(yb, wpb, b_proj, out, BT_, C_, C_);
}

// Round 8
// 211.044 us; speedup vs baseline: 1.2442x; 1.0469x over previous
//
#include <hip/hip_runtime.h>

// ---------------------------------------------------------------------------
// CausalSelfAttention: B=2, T=2048, C=1024, H=16, HD=64
// Inputs fp32, output fp32; internal bf16 MFMA.
// R8: GEMM = R5 reg-staged gemm_bt (fastest measured) + XCD-bijective swizzle
//     (T1). gemm1 writes V transposed [b][h][d][t] (stripe-mapped into qkv's
//     V region) so attn V-staging is conflict-free b128. Q pre-scaled by
//     0.125*log2e at convert time (softmax runs in exp2 domain, no mul).
// ---------------------------------------------------------------------------

#define B_   2
#define T_   2048
#define C_   1024
#define H_   16
#define HD_  64
#define BT_  (B_ * T_)      // 4096
#define C3_  (3 * C_)       // 3072
#define NT_  (T_ / 64)      // 32 q-tiles
#define SCL_ 0.18033688f    // 0.125 * log2(e)

typedef __attribute__((ext_vector_type(8))) __bf16 bf16x8;
typedef __attribute__((ext_vector_type(4))) float  f32x4;
typedef __attribute__((ext_vector_type(8))) unsigned short u16x8;

__device__ __forceinline__ unsigned short f2bf(float f) {
    unsigned int u = __float_as_uint(f);
    u = (u + 0x7fffu + ((u >> 16) & 1u)) >> 16;
    return (unsigned short)u;
}
__device__ __forceinline__ unsigned short bfc(float f) {
    return __builtin_bit_cast(unsigned short, (__bf16)f);
}

// V-transposed storage: logical idx = ((b*16+h)*64+d)*2048 + t, stripe-mapped
// into qkv's V third (rows of 1024 u16 at column 2048 of each 3072-row).
__device__ __forceinline__ size_t vphys(size_t idx) {
    return (idx >> 10) * 3072 + 2048 + (idx & 1023);
}

// ---------------- fused fp32 -> bf16 converts + bias prep ------------------
#define NX8  (BT_ * C_ / 8)      // 524288
#define NWA8 (C3_ * C_ / 8)      // 393216
#define NWP8 (C_ * C_ / 8)       // 131072
#define NB8  (C3_ / 8)           // 384
#define NTOT (NX8 + NWA8 + NWP8 + NB8)
__global__ __launch_bounds__(256) void cvt3(const float* __restrict__ x,
                                            const float* __restrict__ wa,
                                            const float* __restrict__ wp,
                                            const float* __restrict__ ba,
                                            unsigned short* __restrict__ ox,
                                            unsigned short* __restrict__ owa,
                                            unsigned short* __restrict__ owp,
                                            float* __restrict__ obs) {
    int i = blockIdx.x * 256 + threadIdx.x;
    if (i >= NTOT) return;
    if (i >= NX8 + NWA8 + NWP8) {
        // bias prep: scale Q-part of b_attn by SCL_
        int jb = i - (NX8 + NWA8 + NWP8);
        int e  = jb * 8;
        float s = (e < C_) ? SCL_ : 1.0f;
        const float4* p = (const float4*)(ba + e);
        float4 f0 = p[0], f1 = p[1];
        float4* o = (float4*)(obs + e);
        o[0] = make_float4(f0.x * s, f0.y * s, f0.z * s, f0.w * s);
        o[1] = make_float4(f1.x * s, f1.y * s, f1.z * s, f1.w * s);
        return;
    }
    const float* in;
    unsigned short* out;
    int j;
    float s = 1.0f;
    if (i < NX8)             { in = x;  out = ox;  j = i; }
    else if (i < NX8 + NWA8) { in = wa; out = owa; j = i - NX8;
                               if (j < NWP8) s = SCL_; }   // W_attn Q-rows
    else                     { in = wp; out = owp; j = i - NX8 - NWA8; }
    const float4* p = (const float4*)in;
    float4 f0 = p[j * 2];
    float4 f1 = p[j * 2 + 1];
    u16x8 o;
    o[0] = f2bf(f0.x * s); o[1] = f2bf(f0.y * s); o[2] = f2bf(f0.z * s); o[3] = f2bf(f0.w * s);
    o[4] = f2bf(f1.x * s); o[5] = f2bf(f1.y * s); o[6] = f2bf(f1.z * s); o[7] = f2bf(f1.w * s);
    ((u16x8*)out)[j] = o;
}

// ---------------- bf16 GEMM: C[M][N] = A[M][K] * B[N][K]^T + bias ----------
// R5 reg-staged 128x128 tile, BK=64, [72]-padded LDS. 1D grid with bijective
// XCD swizzle (each XCD gets a contiguous by-major chunk -> A-panels L2-hot).
// VSPLIT: blocks with n0>=2048 write V transposed via vphys().
template<int OUT_BF16, int VSPLIT>
__global__ __launch_bounds__(256) void gemm_bt(const unsigned short* __restrict__ A,
                                               const unsigned short* __restrict__ Bm,
                                               const float* __restrict__ bias,
                                               void* __restrict__ Cv,
                                               int M, int N, int K, int nbx) {
    __shared__ __align__(16) unsigned short As[128][72];
    __shared__ __align__(16) unsigned short Bs[128][72];

    const int t    = threadIdx.x;
    const int lane = t & 63;
    const int w    = t >> 6;
    const int wr   = w & 1;
    const int wc   = w >> 1;
    const int l15  = lane & 15;
    const int lhi  = lane >> 4;

    // bijective XCD remap (nwg % 8 == 0 for both GEMMs)
    const int nwg = gridDim.x;
    const int q8  = nwg >> 3;
    const int lin = (int)(blockIdx.x & 7) * q8 + (int)(blockIdx.x >> 3);
    const int bx  = lin % nbx;
    const int by  = lin / nbx;
    const int m0  = by * 128;
    const int n0  = bx * 128;

    f32x4 acc[4][4] = {};

    const int nk = K >> 6;
    for (int kb = 0; kb < nk; ++kb) {
        __syncthreads();
        #pragma unroll
        for (int i = 0; i < 4; ++i) {
            int g   = i * 256 + t;
            int row = g >> 3;
            int kc  = g & 7;
            uint4 va = *(const uint4*)(A  + (size_t)(m0 + row) * K + kb * 64 + kc * 8);
            *(uint4*)(&As[row][kc * 8]) = va;
            uint4 vb = *(const uint4*)(Bm + (size_t)(n0 + row) * K + kb * 64 + kc * 8);
            *(uint4*)(&Bs[row][kc * 8]) = vb;
        }
        __syncthreads();
        #pragma unroll
        for (int kk = 0; kk < 2; ++kk) {
            bf16x8 af[4], bfm[4];
            #pragma unroll
            for (int m = 0; m < 4; ++m)
                af[m] = *(const bf16x8*)(&As[wr * 64 + m * 16 + l15][kk * 32 + lhi * 8]);
            #pragma unroll
            for (int n = 0; n < 4; ++n)
                bfm[n] = *(const bf16x8*)(&Bs[wc * 64 + n * 16 + l15][kk * 32 + lhi * 8]);
            #pragma unroll
            for (int m = 0; m < 4; ++m)
                #pragma unroll
                for (int n = 0; n < 4; ++n)
                    acc[m][n] = __builtin_amdgcn_mfma_f32_16x16x32_bf16(af[m], bfm[n], acc[m][n], 0, 0, 0);
        }
    }

    if (VSPLIT && n0 >= 2048) {
        // V third: write transposed, 4 consecutive t per lane -> one 8B store
        #pragma unroll
        for (int n = 0; n < 4; ++n) {
            int cg = n0 + wc * 64 + n * 16 + l15;
            float bv = bias[cg];
            int d_ = cg - 2048;
            int hh = d_ >> 6;
            int dd = d_ & 63;
            #pragma unroll
            for (int m = 0; m < 4; ++m) {
                int rg0 = m0 + wr * 64 + m * 16 + lhi * 4;
                int bb  = rg0 >> 11;
                int tt  = rg0 & 2047;
                size_t idx = ((size_t)((bb * 16 + hh) * 64 + dd)) * 2048 + tt;
                unsigned short* dst = (unsigned short*)Cv + vphys(idx);
                uint2 pk;
                pk.x = (unsigned int)f2bf(acc[m][n][0] + bv) |
                       ((unsigned int)f2bf(acc[m][n][1] + bv) << 16);
                pk.y = (unsigned int)f2bf(acc[m][n][2] + bv) |
                       ((unsigned int)f2bf(acc[m][n][3] + bv) << 16);
                *(uint2*)dst = pk;
            }
        }
    } else {
        #pragma unroll
        for (int n = 0; n < 4; ++n) {
            int cg = n0 + wc * 64 + n * 16 + l15;
            float bv = bias[cg];
            #pragma unroll
            for (int m = 0; m < 4; ++m) {
                #pragma unroll
                for (int i = 0; i < 4; ++i) {
                    int rg  = m0 + wr * 64 + m * 16 + lhi * 4 + i;
                    float v = acc[m][n][i] + bv;
                    if (OUT_BF16)
                        ((unsigned short*)Cv)[(size_t)rg * N + cg] = f2bf(v);
                    else
                        ((float*)Cv)[(size_t)rg * N + cg] = v;
                }
            }
        }
    }
}

// ---------------- causal flash attention -----------------------------------
// grid = (NT/2, B*H); block 256 (4 waves x 16 q-rows). KV tiles of 128.
// Block handles q-tiles bx then NT-1-bx (17 KV-iters, uniform).
// Swapped QK^T (lane owns q-row l15; in-lane softmax, exp2 domain, Q
// pre-scaled). V read from transposed global layout -> linear b128 staging.
// LDS 35 KB: Ks[128][72] (P aliases after barrier [C]) + Vt[64][136].
__global__ __launch_bounds__(256) void attn_fwd(const unsigned short* __restrict__ qkv,
                                                unsigned short* __restrict__ y) {
    __shared__ __align__(16) unsigned short Ks[128][72];   // 18432 B; P aliases
    __shared__ __align__(16) unsigned short Vt[64][136];   // 17408 B; [d][key]

    const int t    = threadIdx.x;
    const int lane = t & 63;
    const int wv   = t >> 6;
    const int l15  = lane & 15;
    const int lhi  = lane >> 4;
    const int b    = blockIdx.y >> 4;
    const int h    = blockIdx.y & 15;
    const size_t rowbase = (size_t)b * T_ * C3_;
    const int hoff = h * HD_;
    unsigned short* PsW = &Ks[0][0] + wv * (16 * 136);  // wave-private P 16x136

    const unsigned short* krow = qkv + rowbase + C_ + hoff;
    const size_t vIdx0 = ((size_t)(b * 16 + h) * 64) * 2048;

    #pragma unroll 1
    for (int half = 0; half < 2; ++half) {
        const int qt = half ? (NT_ - 1 - (int)blockIdx.x) : (int)blockIdx.x;
        const int q0 = qt * 64;

        bf16x8 qf[2];
        {
            int qrow = q0 + wv * 16 + l15;
            const unsigned short* qp = qkv + rowbase + (size_t)qrow * C3_ + hoff + lhi * 8;
            qf[0] = *(const bf16x8*)(qp);
            qf[1] = *(const bf16x8*)(qp + 32);
        }

        float Mx = -1e30f, Lx = 0.f;     // per-lane: q-row = q0 + wv*16 + l15
        f32x4 oacc[4];
        #pragma unroll
        for (int n = 0; n < 4; ++n) oacc[n] = f32x4{0.f, 0.f, 0.f, 0.f};

        const int niter = (qt + 2) >> 1;
        for (int it = 0; it < niter; ++it) {
            const int k0 = it * 128;
            __syncthreads();                           // [A] prev PV reads done
            // K tile: coalesced b128 row loads
            #pragma unroll
            for (int i = 0; i < 4; ++i) {
                int g   = i * 256 + t;
                int row = g >> 3;
                int kc  = g & 7;
                *(uint4*)(&Ks[row][kc * 8]) =
                    *(const uint4*)(krow + (size_t)(k0 + row) * C3_ + kc * 8);
            }
            // V tile: coalesced reads of transposed V + linear b128 LDS writes
            #pragma unroll
            for (int i = 0; i < 4; ++i) {
                int g  = i * 256 + t;
                int dd = g >> 4;
                int kc = g & 15;
                size_t idx = vIdx0 + (size_t)dd * 2048 + k0 + kc * 8;
                *(u16x8*)(&Vt[dd][kc * 8]) = *(const u16x8*)(qkv + vphys(idx));
            }
            __syncthreads();                           // [B] tile ready

            // S^T = K Q^T  (swapped: lane owns q-row l15); Q pre-scaled
            f32x4 sacc[8];
            #pragma unroll
            for (int n = 0; n < 8; ++n) sacc[n] = f32x4{0.f, 0.f, 0.f, 0.f};
            __builtin_amdgcn_s_setprio(1);
            #pragma unroll
            for (int kk = 0; kk < 2; ++kk) {
                #pragma unroll
                for (int n = 0; n < 8; ++n) {
                    bf16x8 kf = *(const bf16x8*)(&Ks[n * 16 + l15][kk * 32 + lhi * 8]);
                    sacc[n] = __builtin_amdgcn_mfma_f32_16x16x32_bf16(kf, qf[kk], sacc[n], 0, 0, 0);
                }
            }
            __builtin_amdgcn_s_setprio(0);
            __syncthreads();                           // [C] Ks reads done -> P may alias

            // causal mask only (no scale — folded into Q)
            const int qg = q0 + wv * 16 + l15;
            if (k0 + 127 > q0) {
                #pragma unroll
                for (int n = 0; n < 8; ++n) {
                    int kg = k0 + n * 16 + lhi * 4;
                    #pragma unroll
                    for (int r = 0; r < 4; ++r)
                        sacc[n][r] = (kg + r <= qg) ? sacc[n][r] : -1e30f;
                }
            }

            // in-lane softmax (32 vals) + 2-round cross-group reduce
            float vmx = sacc[0][0];
            #pragma unroll
            for (int n = 0; n < 8; ++n)
                #pragma unroll
                for (int r = 0; r < 4; ++r) vmx = fmaxf(vmx, sacc[n][r]);
            vmx = fmaxf(vmx, __shfl_xor(vmx, 16));
            vmx = fmaxf(vmx, __shfl_xor(vmx, 32));
            float Mn = fmaxf(Mx, vmx);
            float al = exp2f(Mx - Mn);
            Mx = Mn;
            float rs = 0.f;
            #pragma unroll
            for (int n = 0; n < 8; ++n)
                #pragma unroll
                for (int r = 0; r < 4; ++r) {
                    float e = exp2f(sacc[n][r] - Mn);
                    sacc[n][r] = e;
                    rs += e;
                }
            rs += __shfl_xor(rs, 16);
            rs += __shfl_xor(rs, 32);
            Lx = Lx * al + rs;

            // rescale O (oacc rows are q = lhi*4 + r)
            #pragma unroll
            for (int r = 0; r < 4; ++r) {
                float ar = __shfl(al, lhi * 4 + r);
                #pragma unroll
                for (int nd = 0; nd < 4; ++nd) oacc[nd][r] *= ar;
            }

            // P -> aliased LDS: packed b64 writes
            #pragma unroll
            for (int n = 0; n < 8; ++n) {
                unsigned int lo = (unsigned int)bfc(sacc[n][0]) | ((unsigned int)bfc(sacc[n][1]) << 16);
                unsigned int hi = (unsigned int)bfc(sacc[n][2]) | ((unsigned int)bfc(sacc[n][3]) << 16);
                uint2 pk; pk.x = lo; pk.y = hi;
                *(uint2*)(PsW + l15 * 136 + n * 16 + lhi * 4) = pk;
            }
            asm volatile("s_waitcnt lgkmcnt(0)" ::: "memory");

            __builtin_amdgcn_s_setprio(1);
            #pragma unroll
            for (int kk = 0; kk < 4; ++kk) {
                bf16x8 pf = *(const bf16x8*)(PsW + l15 * 136 + kk * 32 + lhi * 8);
                #pragma unroll
                for (int nd = 0; nd < 4; ++nd) {
                    bf16x8 vf = *(const bf16x8*)(&Vt[nd * 16 + l15][kk * 32 + lhi * 8]);
                    oacc[nd] = __builtin_amdgcn_mfma_f32_16x16x32_bf16(pf, vf, oacc[nd], 0, 0, 0);
                }
            }
            __builtin_amdgcn_s_setprio(0);
        }

        // epilogue: O / L -> y; L lives at lane q = lhi*4+i
        #pragma unroll
        for (int i = 0; i < 4; ++i) {
            float Lr = __shfl(Lx, lhi * 4 + i);
            float rL = 1.0f / Lr;
            #pragma unroll
            for (int nd = 0; nd < 4; ++nd) {
                int qg = q0 + wv * 16 + lhi * 4 + i;
                y[(size_t)(b * T_ + qg) * C_ + hoff + nd * 16 + l15] = bfc(oacc[nd][i] * rL);
            }
        }
    }
}

// ---------------------------------------------------------------------------
extern "C" void kernel_launch(void* const* d_in, const int* in_sizes, int n_in,
                              void* d_out, int out_size, void* d_ws, size_t ws_size,
                              hipStream_t stream) {
    const float* x      = (const float*)d_in[0];
    const float* W_attn = (const float*)d_in[1];
    const float* b_attn = (const float*)d_in[2];
    const float* W_proj = (const float*)d_in[3];
    const float* b_proj = (const float*)d_in[4];
    float* out = (float*)d_out;

    char* ws = (char*)d_ws;
    unsigned short* xb   = (unsigned short*)(ws);                       // 4096x1024
    unsigned short* wab  = (unsigned short*)(ws + 8388608);             // 3072x1024
    unsigned short* wpb  = (unsigned short*)(ws + 8388608 + 6291456);   // 1024x1024
    unsigned short* qkvb = (unsigned short*)(ws + 16777216);            // 4096x3072
    unsigned short* yb   = (unsigned short*)(ws + 16777216 + 25165824); // 4096x1024
    float*          bs   = (float*)(ws + 16777216 + 25165824 + 8388608); // 3072 f32

    cvt3<<<(NTOT + 255) / 256, 256, 0, stream>>>(x, W_attn, W_proj, b_attn, xb, wab, wpb, bs);

    gemm_bt<1, 1><<<(C3_ / 128) * (BT_ / 128), 256, 0, stream>>>(xb, wab, bs, qkvb, BT_, C3_, C_, C3_ / 128);

    attn_fwd<<<dim3(NT_ / 2, B_ * H_), 256, 0, stream>>>(qkvb, yb);

    gemm_bt<0, 0><<<(C_ / 128) * (BT_ / 128), 256, 0, stream>>>(yb, wpb, b_proj, out, BT_, C_, C_, C_ / 128);
}

// Round 9
// 204.584 us; speedup vs baseline: 1.2835x; 1.0316x over previous
//
#include <hip/hip_runtime.h>

// ---------------------------------------------------------------------------
// CausalSelfAttention: B=2, T=2048, C=1024, H=16, HD=64
// Inputs fp32, output fp32; internal bf16 MFMA.
// R9: attn LDS switched to FRAGMENT-MAJOR layout (conflict-free ds_read_b128
//     for all 36 MFMA-feed reads; XOR term spreads staging writes) + XCD
//     (b,h)-affinity grid remap (K/V working set 2MB/XCD -> L2-resident).
//     GEMMs unchanged from R8.
// ---------------------------------------------------------------------------

#define B_   2
#define T_   2048
#define C_   1024
#define H_   16
#define HD_  64
#define BT_  (B_ * T_)      // 4096
#define C3_  (3 * C_)       // 3072
#define NT_  (T_ / 64)      // 32 q-tiles
#define SCL_ 0.18033688f    // 0.125 * log2(e)

typedef __attribute__((ext_vector_type(8))) __bf16 bf16x8;
typedef __attribute__((ext_vector_type(4))) float  f32x4;
typedef __attribute__((ext_vector_type(8))) unsigned short u16x8;

__device__ __forceinline__ unsigned short f2bf(float f) {
    unsigned int u = __float_as_uint(f);
    u = (u + 0x7fffu + ((u >> 16) & 1u)) >> 16;
    return (unsigned short)u;
}
__device__ __forceinline__ unsigned short bfc(float f) {
    return __builtin_bit_cast(unsigned short, (__bf16)f);
}

// V-transposed storage: logical idx = ((b*16+h)*64+d)*2048 + t, stripe-mapped
// into qkv's V third (rows of 1024 u16 at column 2048 of each 3072-row).
__device__ __forceinline__ size_t vphys(size_t idx) {
    return (idx >> 10) * 3072 + 2048 + (idx & 1023);
}

// ---------------- fused fp32 -> bf16 converts + bias prep ------------------
#define NX8  (BT_ * C_ / 8)      // 524288
#define NWA8 (C3_ * C_ / 8)      // 393216
#define NWP8 (C_ * C_ / 8)       // 131072
#define NB8  (C3_ / 8)           // 384
#define NTOT (NX8 + NWA8 + NWP8 + NB8)
__global__ __launch_bounds__(256) void cvt3(const float* __restrict__ x,
                                            const float* __restrict__ wa,
                                            const float* __restrict__ wp,
                                            const float* __restrict__ ba,
                                            unsigned short* __restrict__ ox,
                                            unsigned short* __restrict__ owa,
                                            unsigned short* __restrict__ owp,
                                            float* __restrict__ obs) {
    int i = blockIdx.x * 256 + threadIdx.x;
    if (i >= NTOT) return;
    if (i >= NX8 + NWA8 + NWP8) {
        int jb = i - (NX8 + NWA8 + NWP8);
        int e  = jb * 8;
        float s = (e < C_) ? SCL_ : 1.0f;
        const float4* p = (const float4*)(ba + e);
        float4 f0 = p[0], f1 = p[1];
        float4* o = (float4*)(obs + e);
        o[0] = make_float4(f0.x * s, f0.y * s, f0.z * s, f0.w * s);
        o[1] = make_float4(f1.x * s, f1.y * s, f1.z * s, f1.w * s);
        return;
    }
    const float* in;
    unsigned short* out;
    int j;
    float s = 1.0f;
    if (i < NX8)             { in = x;  out = ox;  j = i; }
    else if (i < NX8 + NWA8) { in = wa; out = owa; j = i - NX8;
                               if (j < NWP8) s = SCL_; }   // W_attn Q-rows
    else                     { in = wp; out = owp; j = i - NX8 - NWA8; }
    const float4* p = (const float4*)in;
    float4 f0 = p[j * 2];
    float4 f1 = p[j * 2 + 1];
    u16x8 o;
    o[0] = f2bf(f0.x * s); o[1] = f2bf(f0.y * s); o[2] = f2bf(f0.z * s); o[3] = f2bf(f0.w * s);
    o[4] = f2bf(f1.x * s); o[5] = f2bf(f1.y * s); o[6] = f2bf(f1.z * s); o[7] = f2bf(f1.w * s);
    ((u16x8*)out)[j] = o;
}

// ---------------- bf16 GEMM: C[M][N] = A[M][K] * B[N][K]^T + bias ----------
// R5 reg-staged 128x128 tile, BK=64, [72]-padded LDS, bijective XCD swizzle.
// VSPLIT: blocks with n0>=2048 write V transposed via vphys().
template<int OUT_BF16, int VSPLIT>
__global__ __launch_bounds__(256) void gemm_bt(const unsigned short* __restrict__ A,
                                               const unsigned short* __restrict__ Bm,
                                               const float* __restrict__ bias,
                                               void* __restrict__ Cv,
                                               int M, int N, int K, int nbx) {
    __shared__ __align__(16) unsigned short As[128][72];
    __shared__ __align__(16) unsigned short Bs[128][72];

    const int t    = threadIdx.x;
    const int lane = t & 63;
    const int w    = t >> 6;
    const int wr   = w & 1;
    const int wc   = w >> 1;
    const int l15  = lane & 15;
    const int lhi  = lane >> 4;

    const int nwg = gridDim.x;
    const int q8  = nwg >> 3;
    const int lin = (int)(blockIdx.x & 7) * q8 + (int)(blockIdx.x >> 3);
    const int bx  = lin % nbx;
    const int by  = lin / nbx;
    const int m0  = by * 128;
    const int n0  = bx * 128;

    f32x4 acc[4][4] = {};

    const int nk = K >> 6;
    for (int kb = 0; kb < nk; ++kb) {
        __syncthreads();
        #pragma unroll
        for (int i = 0; i < 4; ++i) {
            int g   = i * 256 + t;
            int row = g >> 3;
            int kc  = g & 7;
            uint4 va = *(const uint4*)(A  + (size_t)(m0 + row) * K + kb * 64 + kc * 8);
            *(uint4*)(&As[row][kc * 8]) = va;
            uint4 vb = *(const uint4*)(Bm + (size_t)(n0 + row) * K + kb * 64 + kc * 8);
            *(uint4*)(&Bs[row][kc * 8]) = vb;
        }
        __syncthreads();
        #pragma unroll
        for (int kk = 0; kk < 2; ++kk) {
            bf16x8 af[4], bfm[4];
            #pragma unroll
            for (int m = 0; m < 4; ++m)
                af[m] = *(const bf16x8*)(&As[wr * 64 + m * 16 + l15][kk * 32 + lhi * 8]);
            #pragma unroll
            for (int n = 0; n < 4; ++n)
                bfm[n] = *(const bf16x8*)(&Bs[wc * 64 + n * 16 + l15][kk * 32 + lhi * 8]);
            #pragma unroll
            for (int m = 0; m < 4; ++m)
                #pragma unroll
                for (int n = 0; n < 4; ++n)
                    acc[m][n] = __builtin_amdgcn_mfma_f32_16x16x32_bf16(af[m], bfm[n], acc[m][n], 0, 0, 0);
        }
    }

    if (VSPLIT && n0 >= 2048) {
        #pragma unroll
        for (int n = 0; n < 4; ++n) {
            int cg = n0 + wc * 64 + n * 16 + l15;
            float bv = bias[cg];
            int d_ = cg - 2048;
            int hh = d_ >> 6;
            int dd = d_ & 63;
            #pragma unroll
            for (int m = 0; m < 4; ++m) {
                int rg0 = m0 + wr * 64 + m * 16 + lhi * 4;
                int bb  = rg0 >> 11;
                int tt  = rg0 & 2047;
                size_t idx = ((size_t)((bb * 16 + hh) * 64 + dd)) * 2048 + tt;
                unsigned short* dst = (unsigned short*)Cv + vphys(idx);
                uint2 pk;
                pk.x = (unsigned int)f2bf(acc[m][n][0] + bv) |
                       ((unsigned int)f2bf(acc[m][n][1] + bv) << 16);
                pk.y = (unsigned int)f2bf(acc[m][n][2] + bv) |
                       ((unsigned int)f2bf(acc[m][n][3] + bv) << 16);
                *(uint2*)dst = pk;
            }
        }
    } else {
        #pragma unroll
        for (int n = 0; n < 4; ++n) {
            int cg = n0 + wc * 64 + n * 16 + l15;
            float bv = bias[cg];
            #pragma unroll
            for (int m = 0; m < 4; ++m) {
                #pragma unroll
                for (int i = 0; i < 4; ++i) {
                    int rg  = m0 + wr * 64 + m * 16 + lhi * 4 + i;
                    float v = acc[m][n][i] + bv;
                    if (OUT_BF16)
                        ((unsigned short*)Cv)[(size_t)rg * N + cg] = f2bf(v);
                    else
                        ((float*)Cv)[(size_t)rg * N + cg] = v;
                }
            }
        }
    }
}

// ---------------- causal flash attention -----------------------------------
// grid = 512 (1D, XCD-affine: xcd=bid&7 owns 4 (b,h)); block 256 = 4 waves.
// KV tiles of 128; q-tile pair (qp, NT-1-qp) per block (uniform 17 iters).
// LDS (32 KB): KL[8192] u16 K frag-major (P aliases, 4KB/wave), VL[8192] u16.
// Fragment-major slot: (grp*4+lhi)*16 + (l15 ^ lhi ^ ((kk&1)<<2)); MFMA-feed
// ds_read_b128 is conflict-free (lane -> distinct 16B slot, phases spread).
__global__ __launch_bounds__(256) void attn_fwd(const unsigned short* __restrict__ qkv,
                                                unsigned short* __restrict__ y) {
    __shared__ __align__(16) unsigned short KL[8192];   // 16 KB; P aliases
    __shared__ __align__(16) unsigned short VL[8192];   // 16 KB

    const int t    = threadIdx.x;
    const int lane = t & 63;
    const int wv   = t >> 6;
    const int l15  = lane & 15;
    const int lhi  = lane >> 4;

    // XCD-affinity remap: xcd = bid & 7 (dispatch round-robin), 64 blocks/XCD
    const int bid = blockIdx.x;
    const int idx = (bid >> 3) + (bid & 7) * 64;   // 0..511, XCD-major
    const int bh  = idx >> 4;                      // 4 bh per XCD chunk of 64
    const int qp  = idx & 15;
    const int b   = bh >> 4;
    const int h   = bh & 15;
    const size_t rowbase = (size_t)b * T_ * C3_;
    const int hoff = h * HD_;

    unsigned short* Pw = KL + wv * 2048;           // wave-private P (4 KB)

    // fragment-read offsets (u16 units), kk = 0..3
    int voff[4];
    #pragma unroll
    for (int kk = 0; kk < 4; ++kk)
        voff[kk] = ((kk * 4 + lhi) * 16 + (l15 ^ lhi ^ ((kk & 1) << 2))) * 8;

    const unsigned short* krow = qkv + rowbase + C_ + hoff;
    const size_t vIdx0 = ((size_t)(b * 16 + h) * 64) * 2048;

    #pragma unroll 1
    for (int half = 0; half < 2; ++half) {
        const int qt = half ? (NT_ - 1 - qp) : qp;
        const int q0 = qt * 64;

        bf16x8 qf[2];
        {
            int qrow = q0 + wv * 16 + l15;
            const unsigned short* qp_ = qkv + rowbase + (size_t)qrow * C3_ + hoff + lhi * 8;
            qf[0] = *(const bf16x8*)(qp_);
            qf[1] = *(const bf16x8*)(qp_ + 32);
        }

        float Mx = -1e30f, Lx = 0.f;     // per-lane: q-row = q0 + wv*16 + l15
        f32x4 oacc[4];
        #pragma unroll
        for (int n = 0; n < 4; ++n) oacc[n] = f32x4{0.f, 0.f, 0.f, 0.f};

        const int niter = (qt + 2) >> 1;
        for (int it = 0; it < niter; ++it) {
            const int k0 = it * 128;
            __syncthreads();                           // [A] prev PV reads done
            // K tile -> frag-major LDS
            #pragma unroll
            for (int i = 0; i < 4; ++i) {
                int g   = i * 256 + t;
                int row = g >> 3, cc = g & 7;
                int n_ = row >> 4, f15 = row & 15, fkk = cc >> 2, fhi = cc & 3;
                int slot = ((n_ * 2 + fkk) * 4 + fhi) * 16 + (f15 ^ fhi ^ ((fkk & 1) << 2));
                *(u16x8*)(KL + slot * 8) =
                    *(const u16x8*)(krow + (size_t)(k0 + row) * C3_ + cc * 8);
            }
            // V tile (from transposed global) -> frag-major LDS
            #pragma unroll
            for (int i = 0; i < 4; ++i) {
                int g  = i * 256 + t;
                int d  = g >> 4, kc = g & 15;
                int nd = d >> 4, f15 = d & 15, fkk = kc >> 2, fhi = kc & 3;
                int slot = ((nd * 4 + fkk) * 4 + fhi) * 16 + (f15 ^ fhi ^ ((fkk & 1) << 2));
                size_t gidx = vIdx0 + (size_t)d * 2048 + k0 + kc * 8;
                *(u16x8*)(VL + slot * 8) = *(const u16x8*)(qkv + vphys(gidx));
            }
            __syncthreads();                           // [B] tile ready

            // S^T = K Q^T  (swapped: lane owns q-row l15); Q pre-scaled
            f32x4 sacc[8];
            #pragma unroll
            for (int n = 0; n < 8; ++n) sacc[n] = f32x4{0.f, 0.f, 0.f, 0.f};
            __builtin_amdgcn_s_setprio(1);
            #pragma unroll
            for (int kk = 0; kk < 2; ++kk) {
                #pragma unroll
                for (int n = 0; n < 8; ++n) {
                    bf16x8 kf = *(const bf16x8*)(KL + n * 1024 + voff[kk]);
                    sacc[n] = __builtin_amdgcn_mfma_f32_16x16x32_bf16(kf, qf[kk], sacc[n], 0, 0, 0);
                }
            }
            __builtin_amdgcn_s_setprio(0);
            __syncthreads();                           // [C] K reads done -> P may alias

            // causal mask (scale folded into Q)
            const int qg = q0 + wv * 16 + l15;
            if (k0 + 127 > q0) {
                #pragma unroll
                for (int n = 0; n < 8; ++n) {
                    int kg = k0 + n * 16 + lhi * 4;
                    #pragma unroll
                    for (int r = 0; r < 4; ++r)
                        sacc[n][r] = (kg + r <= qg) ? sacc[n][r] : -1e30f;
                }
            }

            // in-lane softmax + 2-round cross-group reduce
            float vmx = sacc[0][0];
            #pragma unroll
            for (int n = 0; n < 8; ++n)
                #pragma unroll
                for (int r = 0; r < 4; ++r) vmx = fmaxf(vmx, sacc[n][r]);
            vmx = fmaxf(vmx, __shfl_xor(vmx, 16));
            vmx = fmaxf(vmx, __shfl_xor(vmx, 32));
            float Mn = fmaxf(Mx, vmx);
            float al = exp2f(Mx - Mn);
            Mx = Mn;
            float rs = 0.f;
            #pragma unroll
            for (int n = 0; n < 8; ++n)
                #pragma unroll
                for (int r = 0; r < 4; ++r) {
                    float e = exp2f(sacc[n][r] - Mn);
                    sacc[n][r] = e;
                    rs += e;
                }
            rs += __shfl_xor(rs, 16);
            rs += __shfl_xor(rs, 32);
            Lx = Lx * al + rs;

            // rescale O (oacc rows are q = lhi*4 + r)
            #pragma unroll
            for (int r = 0; r < 4; ++r) {
                float ar = __shfl(al, lhi * 4 + r);
                #pragma unroll
                for (int nd = 0; nd < 4; ++nd) oacc[nd][r] *= ar;
            }

            // P -> frag-major aliased LDS: lane owns cols n*16+lhi*4..+3 of
            // row l15. kkR=n>>1, lhiR=((n&1)<<1)|(lhi>>1), j0=(lhi&1)*4.
            #pragma unroll
            for (int n = 0; n < 8; ++n) {
                const int kkR  = n >> 1;
                const int lhiR = ((n & 1) << 1) | (lhi >> 1);
                const int j0   = (lhi & 1) * 4;
                const int slot = (kkR * 4 + lhiR) * 16 + (l15 ^ lhiR ^ ((kkR & 1) << 2));
                uint2 pk;
                pk.x = (unsigned int)bfc(sacc[n][0]) | ((unsigned int)bfc(sacc[n][1]) << 16);
                pk.y = (unsigned int)bfc(sacc[n][2]) | ((unsigned int)bfc(sacc[n][3]) << 16);
                *(uint2*)(Pw + slot * 8 + j0) = pk;
            }
            asm volatile("s_waitcnt lgkmcnt(0)" ::: "memory");
            __builtin_amdgcn_sched_barrier(0);

            __builtin_amdgcn_s_setprio(1);
            #pragma unroll
            for (int kk = 0; kk < 4; ++kk) {
                bf16x8 pf = *(const bf16x8*)(Pw + voff[kk]);
                #pragma unroll
                for (int nd = 0; nd < 4; ++nd) {
                    bf16x8 vf = *(const bf16x8*)(VL + nd * 2048 + voff[kk]);
                    oacc[nd] = __builtin_amdgcn_mfma_f32_16x16x32_bf16(pf, vf, oacc[nd], 0, 0, 0);
                }
            }
            __builtin_amdgcn_s_setprio(0);
        }

        // epilogue: O / L -> y; L lives at lane q = lhi*4+i
        #pragma unroll
        for (int i = 0; i < 4; ++i) {
            float Lr = __shfl(Lx, lhi * 4 + i);
            float rL = 1.0f / Lr;
            #pragma unroll
            for (int nd = 0; nd < 4; ++nd) {
                int qg = q0 + wv * 16 + lhi * 4 + i;
                y[(size_t)(b * T_ + qg) * C_ + hoff + nd * 16 + l15] = bfc(oacc[nd][i] * rL);
            }
        }
    }
}

// ---------------------------------------------------------------------------
extern "C" void kernel_launch(void* const* d_in, const int* in_sizes, int n_in,
                              void* d_out, int out_size, void* d_ws, size_t ws_size,
                              hipStream_t stream) {
    const float* x      = (const float*)d_in[0];
    const float* W_attn = (const float*)d_in[1];
    const float* b_attn = (const float*)d_in[2];
    const float* W_proj = (const float*)d_in[3];
    const float* b_proj = (const float*)d_in[4];
    float* out = (float*)d_out;

    char* ws = (char*)d_ws;
    unsigned short* xb   = (unsigned short*)(ws);                       // 4096x1024
    unsigned short* wab  = (unsigned short*)(ws + 8388608);             // 3072x1024
    unsigned short* wpb  = (unsigned short*)(ws + 8388608 + 6291456);   // 1024x1024
    unsigned short* qkvb = (unsigned short*)(ws + 16777216);            // 4096x3072
    unsigned short* yb   = (unsigned short*)(ws + 16777216 + 25165824); // 4096x1024
    float*          bs   = (float*)(ws + 16777216 + 25165824 + 8388608); // 3072 f32

    cvt3<<<(NTOT + 255) / 256, 256, 0, stream>>>(x, W_attn, W_proj, b_attn, xb, wab, wpb, bs);

    gemm_bt<1, 1><<<(C3_ / 128) * (BT_ / 128), 256, 0, stream>>>(xb, wab, bs, qkvb, BT_, C3_, C_, C3_ / 128);

    attn_fwd<<<512, 256, 0, stream>>>(qkvb, yb);

    gemm_bt<0, 0><<<(C_ / 128) * (BT_ / 128), 256, 0, stream>>>(yb, wpb, b_proj, out, BT_, C_, C_, C_ / 128);
}